// Round 11
// baseline (546.885 us; speedup 1.0000x reference)
//
#include <hip/hip_runtime.h>
#include <math.h>

namespace {
constexpr int   NB   = 25;     // basis functions
constexpr int   TS   = 301;    // time steps
constexpr int   TPAD = 304;    // padded table stride
constexpr float DT   = 0.01f;
constexpr float TAU  = 3.0f;
constexpr float AX   = 2.0f;
constexpr float AZ   = 48.0f;
constexpr float BZ   = 12.0f;  // AZ/4
constexpr int   ROWS = 131072; // BATCH * DOF
}

// ws layout (floats): [0..TPAD) = A_t, [TPAD..2*TPAD) = B_t,
//                     [(2+n)*TPAD + t] = H_t[n]
__global__ __launch_bounds__(512)
void dmp_precompute(const float* __restrict__ c, const float* __restrict__ s2,
                    float* __restrict__ ws) {
  __shared__ float g[TS][NB];
  __shared__ float cS[NB], vS[NB];
  const int tid = threadIdx.x;
  if (tid < NB) { cS[tid] = c[tid]; vS[tid] = s2[tid]; }
  __syncthreads();
  const float q = 1.0f - AX / TAU * DT;   // cx multiplier per step
  for (int i = tid; i < TS; i += 512) {
    float cx = powf(q, (float)(i + 1));   // cx updated BEFORE use in ref
    float p[NB]; float sum = 0.f;
    #pragma unroll
    for (int n = 0; n < NB; ++n) {
      float d = cx - cS[n];
      p[n] = expf(-0.5f * d * d / vS[n]);
      sum += p[n];
    }
    float m = cx / sum;
    #pragma unroll
    for (int n = 0; n < NB; ++n) g[i][n] = p[n] * m;
  }
  __syncthreads();
  // 27 independent linear-response recurrences (lanes 0..26)
  if (tid < NB + 2) {
    float y, gl;
    if (tid == 0)      { y = 1.f; gl = 0.f; }   // response to y0
    else if (tid == 1) { y = 0.f; gl = 1.f; }   // response to goal
    else               { y = 0.f; gl = 0.f; }   // response to unit w_n
    float z = 0.f;
    const int nn = (tid >= 2) ? (tid - 2) : 0;
    float* dst = ws + tid * TPAD;
    for (int t = 0; t < TS; ++t) {
      float fx = (tid >= 2) ? g[t][nn] : 0.f;
      float dy = z / TAU;
      float dz = (AZ * (BZ * (gl - y) - z) + fx) / TAU;
      y += dy * DT;
      z += dz * DT;
      dst[t] = y;
    }
  }
}

// Block = 512 threads = 8 waves, 256 rows. Wave role: dof = w&1,
// t-group = (w>>1)&1 (0 -> chunks {0,1,2}, 1 -> chunks {3,4}),
// row-half = w>>2. Role-split keeps per-wave table regs at 83/58 so
// total demand fits under the 128-VGPR cap (R10 failure: 210 live regs
// -> scratch spills, FETCH 673 MB). Row broadcast via uniform-address
// ds_read_b128 from the block-staged x tile; FMAs consume float4
// components directly (no xv copy). Stores coalesced 256 B chunks.
__global__ __launch_bounds__(512, 4)
void dmp_main(const float* __restrict__ x, const float* __restrict__ scale,
              const float* __restrict__ ws, float* __restrict__ out) {
  __shared__ float sh[256 * 28];
  const int tid  = threadIdx.x;
  const int w    = tid >> 6;
  const int lane = tid & 63;
  const int dof  = w & 1;
  const int tg   = (w >> 1) & 1;
  const int half = w >> 2;

  // ---- stage 256 rows x 27 floats -> LDS (stride 28), coalesced ----
  {
    const float* __restrict__ xsrc = x + (size_t)blockIdx.x * (256 * 27);
    for (int e = tid; e < 256 * 27; e += 512) {
      const int r = e / 27;
      const int k = e - r * 27;
      sh[r * 28 + k] = xsrc[e];
    }
  }
  __syncthreads();

  float vs0 = scale[dof * 27], vs1 = scale[dof * 27 + 1];
  asm volatile("" : "+v"(vs0), "+v"(vs1));
  const int    lrow0 = half * 128 + dof;
  const size_t gbase = (size_t)blockIdx.x * 256 + lrow0;

  if (tg == 0) {
    // ---- chunks 0,1,2 : tables = 83 VGPRs ----
    float a0, a1, a2, b0, b1, b2, h0[NB], h1[NB], h2[NB];
    {
      const int t0 = lane, t1 = lane + 64, t2 = lane + 128;
      a0 = ws[t0]; a1 = ws[t1]; a2 = ws[t2];
      b0 = ws[TPAD + t0]; b1 = ws[TPAD + t1]; b2 = ws[TPAD + t2];
      #pragma unroll
      for (int k = 0; k < NB; ++k) {
        const float sk = scale[dof * 27 + 2 + k];
        const float* hp = ws + (2 + k) * TPAD;
        h0[k] = hp[t0] * sk; h1[k] = hp[t1] * sk; h2[k] = hp[t2] * sk;
      }
    }
    asm volatile("" : "+v"(a0), "+v"(a1), "+v"(a2), "+v"(b0), "+v"(b1), "+v"(b2));
    #pragma unroll
    for (int k = 0; k < NB; ++k)
      asm volatile("" : "+v"(h0[k]), "+v"(h1[k]), "+v"(h2[k]));

    #pragma unroll 1
    for (int i = 0; i < 64; ++i) {
      const float* __restrict__ rp = sh + (lrow0 + 2 * i) * 28;
      const float4 q0 = *(const float4*)(rp);
      const float4 q1 = *(const float4*)(rp + 4);
      const float4 q2 = *(const float4*)(rp + 8);
      const float4 q3 = *(const float4*)(rp + 12);
      const float4 q4 = *(const float4*)(rp + 16);
      const float4 q5 = *(const float4*)(rp + 20);
      const float4 q6 = *(const float4*)(rp + 24);
      const float y0s = q0.x * vs0;
      const float gs  = q0.y * vs1;
      const float dd  = gs - y0s;
      float A0 = 0.f, A1 = 0.f, B0 = 0.f, B1 = 0.f, C0 = 0.f, C1 = 0.f;
      A0 = fmaf(q0.z, h0[0], A0); A1 = fmaf(q0.w, h0[1], A1);
      B0 = fmaf(q0.z, h1[0], B0); B1 = fmaf(q0.w, h1[1], B1);
      C0 = fmaf(q0.z, h2[0], C0); C1 = fmaf(q0.w, h2[1], C1);
      #pragma unroll
      for (int j = 0; j < 4; ++j) {
        const float4 qq = (j == 0) ? q1 : (j == 1) ? q2 : (j == 2) ? q3 : q4;
        const int k = 2 + 4 * j;
        A0 = fmaf(qq.x, h0[k],     A0); A1 = fmaf(qq.y, h0[k + 1], A1);
        A0 = fmaf(qq.z, h0[k + 2], A0); A1 = fmaf(qq.w, h0[k + 3], A1);
        B0 = fmaf(qq.x, h1[k],     B0); B1 = fmaf(qq.y, h1[k + 1], B1);
        B0 = fmaf(qq.z, h1[k + 2], B0); B1 = fmaf(qq.w, h1[k + 3], B1);
        C0 = fmaf(qq.x, h2[k],     C0); C1 = fmaf(qq.y, h2[k + 1], C1);
        C0 = fmaf(qq.z, h2[k + 2], C0); C1 = fmaf(qq.w, h2[k + 3], C1);
      }
      A0 = fmaf(q5.x, h0[18], A0); A1 = fmaf(q5.y, h0[19], A1);
      A0 = fmaf(q5.z, h0[20], A0); A1 = fmaf(q5.w, h0[21], A1);
      B0 = fmaf(q5.x, h1[18], B0); B1 = fmaf(q5.y, h1[19], B1);
      B0 = fmaf(q5.z, h1[20], B0); B1 = fmaf(q5.w, h1[21], B1);
      C0 = fmaf(q5.x, h2[18], C0); C1 = fmaf(q5.y, h2[19], C1);
      C0 = fmaf(q5.z, h2[20], C0); C1 = fmaf(q5.w, h2[21], C1);
      A0 = fmaf(q6.x, h0[22], A0); A1 = fmaf(q6.y, h0[23], A1);
      A0 = fmaf(q6.z, h0[24], A0);
      B0 = fmaf(q6.x, h1[22], B0); B1 = fmaf(q6.y, h1[23], B1);
      B0 = fmaf(q6.z, h1[24], B0);
      C0 = fmaf(q6.x, h2[22], C0); C1 = fmaf(q6.y, h2[23], C1);
      C0 = fmaf(q6.z, h2[24], C0);
      float* __restrict__ orow = out + (gbase + 2 * (size_t)i) * TS;
      orow[lane]       = fmaf(a0, y0s, fmaf(b0, gs, dd * (A0 + A1)));
      orow[lane + 64]  = fmaf(a1, y0s, fmaf(b1, gs, dd * (B0 + B1)));
      orow[lane + 128] = fmaf(a2, y0s, fmaf(b2, gs, dd * (C0 + C1)));
    }
  } else {
    // ---- chunks 3,4 : tables = 58 VGPRs (chunk 4 masked, 45 lanes) ----
    float a3, a4, b3, b4, h3[NB], h4[NB];
    const bool tail = (lane < TS - 256);
    {
      const int t3 = lane + 192;
      const int t4 = (lane + 256 < TS) ? (lane + 256) : (TS - 1);
      a3 = ws[t3]; a4 = ws[t4];
      b3 = ws[TPAD + t3]; b4 = ws[TPAD + t4];
      #pragma unroll
      for (int k = 0; k < NB; ++k) {
        const float sk = scale[dof * 27 + 2 + k];
        const float* hp = ws + (2 + k) * TPAD;
        h3[k] = hp[t3] * sk; h4[k] = hp[t4] * sk;
      }
    }
    asm volatile("" : "+v"(a3), "+v"(a4), "+v"(b3), "+v"(b4));
    #pragma unroll
    for (int k = 0; k < NB; ++k)
      asm volatile("" : "+v"(h3[k]), "+v"(h4[k]));

    #pragma unroll 1
    for (int i = 0; i < 64; ++i) {
      const float* __restrict__ rp = sh + (lrow0 + 2 * i) * 28;
      const float4 q0 = *(const float4*)(rp);
      const float4 q1 = *(const float4*)(rp + 4);
      const float4 q2 = *(const float4*)(rp + 8);
      const float4 q3 = *(const float4*)(rp + 12);
      const float4 q4 = *(const float4*)(rp + 16);
      const float4 q5 = *(const float4*)(rp + 20);
      const float4 q6 = *(const float4*)(rp + 24);
      const float y0s = q0.x * vs0;
      const float gs  = q0.y * vs1;
      const float dd  = gs - y0s;
      float D0 = 0.f, D1 = 0.f, E0 = 0.f, E1 = 0.f;
      D0 = fmaf(q0.z, h3[0], D0); D1 = fmaf(q0.w, h3[1], D1);
      E0 = fmaf(q0.z, h4[0], E0); E1 = fmaf(q0.w, h4[1], E1);
      #pragma unroll
      for (int j = 0; j < 4; ++j) {
        const float4 qq = (j == 0) ? q1 : (j == 1) ? q2 : (j == 2) ? q3 : q4;
        const int k = 2 + 4 * j;
        D0 = fmaf(qq.x, h3[k],     D0); D1 = fmaf(qq.y, h3[k + 1], D1);
        D0 = fmaf(qq.z, h3[k + 2], D0); D1 = fmaf(qq.w, h3[k + 3], D1);
        E0 = fmaf(qq.x, h4[k],     E0); E1 = fmaf(qq.y, h4[k + 1], E1);
        E0 = fmaf(qq.z, h4[k + 2], E0); E1 = fmaf(qq.w, h4[k + 3], E1);
      }
      D0 = fmaf(q5.x, h3[18], D0); D1 = fmaf(q5.y, h3[19], D1);
      D0 = fmaf(q5.z, h3[20], D0); D1 = fmaf(q5.w, h3[21], D1);
      E0 = fmaf(q5.x, h4[18], E0); E1 = fmaf(q5.y, h4[19], E1);
      E0 = fmaf(q5.z, h4[20], E0); E1 = fmaf(q5.w, h4[21], E1);
      D0 = fmaf(q6.x, h3[22], D0); D1 = fmaf(q6.y, h3[23], D1);
      D0 = fmaf(q6.z, h3[24], D0);
      E0 = fmaf(q6.x, h4[22], E0); E1 = fmaf(q6.y, h4[23], E1);
      E0 = fmaf(q6.z, h4[24], E0);
      float* __restrict__ orow = out + (gbase + 2 * (size_t)i) * TS;
      orow[lane + 192] = fmaf(a3, y0s, fmaf(b3, gs, dd * (D0 + D1)));
      if (tail)
        orow[lane + 256] = fmaf(a4, y0s, fmaf(b4, gs, dd * (E0 + E1)));
    }
  }
}

extern "C" void kernel_launch(void* const* d_in, const int* in_sizes, int n_in,
                              void* d_out, int out_size, void* d_ws, size_t ws_size,
                              hipStream_t stream) {
  const float* x  = (const float*)d_in[0];
  const float* c  = (const float*)d_in[1];
  const float* s2 = (const float*)d_in[2];
  const float* sc = (const float*)d_in[3];
  float* ws  = (float*)d_ws;   // needs 27*304*4 = 32,832 bytes
  float* out = (float*)d_out;

  hipLaunchKernelGGL(dmp_precompute, dim3(1), dim3(512), 0, stream, c, s2, ws);
  hipLaunchKernelGGL(dmp_main, dim3(ROWS / 256), dim3(512), 0, stream,
                     x, sc, ws, out);
}

// Round 12
// 123.409 us; speedup vs baseline: 4.4315x; 4.4315x over previous
//
#include <hip/hip_runtime.h>
#include <math.h>

namespace {
constexpr int   NB   = 25;     // basis functions
constexpr int   TS   = 301;    // time steps
constexpr int   REC  = 28;     // floats per (dof,t) record: h[25], A, B, pad
constexpr float DT   = 0.01f;
constexpr float TAU  = 3.0f;
constexpr float AX   = 2.0f;
constexpr float AZ   = 48.0f;
constexpr float BZ   = 12.0f;  // AZ/4
constexpr int   BATCH = 65536;
constexpr int   BR   = 128;    // rows (of one dof) per block
}

// ws2 layout: [dof][t][REC] = { H_k[t]*scale[dof*27+2+k] (k<25), A[t], B[t], 0 }
__global__ __launch_bounds__(512)
void dmp_precompute(const float* __restrict__ c, const float* __restrict__ s2,
                    const float* __restrict__ scale, float* __restrict__ ws2) {
  __shared__ float g[TS][NB];
  __shared__ float H[NB + 2][304];
  __shared__ float cS[NB], vS[NB];
  const int tid = threadIdx.x;
  if (tid < NB) { cS[tid] = c[tid]; vS[tid] = s2[tid]; }
  __syncthreads();
  const float q = 1.0f - AX / TAU * DT;   // cx multiplier per step
  for (int i = tid; i < TS; i += 512) {
    float cx = powf(q, (float)(i + 1));   // cx updated BEFORE use in ref
    float p[NB]; float sum = 0.f;
    #pragma unroll
    for (int n = 0; n < NB; ++n) {
      float d = cx - cS[n];
      p[n] = expf(-0.5f * d * d / vS[n]);
      sum += p[n];
    }
    float m = cx / sum;
    #pragma unroll
    for (int n = 0; n < NB; ++n) g[i][n] = p[n] * m;
  }
  __syncthreads();
  if (tid < NB + 2) {
    float y, gl;
    if (tid == 0)      { y = 1.f; gl = 0.f; }   // response to y0
    else if (tid == 1) { y = 0.f; gl = 1.f; }   // response to goal
    else               { y = 0.f; gl = 0.f; }   // response to unit w_n
    float z = 0.f;
    const int nn = (tid >= 2) ? (tid - 2) : 0;
    for (int t = 0; t < TS; ++t) {
      float fx = (tid >= 2) ? g[t][nn] : 0.f;
      float dy = z / TAU;
      float dz = (AZ * (BZ * (gl - y) - z) + fx) / TAU;
      y += dy * DT;
      z += dz * DT;
      H[tid][t] = y;
    }
  }
  __syncthreads();
  constexpr int TOT = 2 * TS * REC;
  for (int idx = tid; idx < TOT; idx += 512) {
    const int dof = idx / (TS * REC);
    const int rem = idx - dof * (TS * REC);
    const int t   = rem / REC;
    const int k   = rem - t * REC;
    float v;
    if (k < NB)            v = H[2 + k][t] * scale[dof * 27 + 2 + k];
    else if (k == NB)      v = H[0][t];   // A
    else if (k == NB + 1)  v = H[1][t];   // B
    else                   v = 0.f;
    ws2[idx] = v;
  }
}

// Block = 128 threads = 2 waves; dof = blockIdx&1 (WAVE-UNIFORM -> the
// h-record pointer is provably uniform and the compiler emits s_load
// naturally; R6 failed because dof was threadIdx-derived). Lane = one row:
// its 27 x-floats live in ~45 VGPRs total (no big arrays, no pins --
// R10/R11 failure: 135-reg tables forced arrays into scratch, FETCH 1.1GB).
// Per t: s_load 28-float record (K$-hot: 67KB reused by all 1024 blocks),
// 26 FMA/lane -> 1 output. Outputs staged in per-wave [64][33] LDS tile
// (2-way bank aliasing = free) and flushed every 32 t as two 128B
// coalesced row-chunks per store instruction.
__global__ __launch_bounds__(128, 4)
void dmp_main(const float* __restrict__ x, const float* __restrict__ scale,
              const float* __restrict__ ws2, float* __restrict__ out) {
  __shared__ float tile[2][64][33];
  const int blk  = blockIdx.x;
  const int dof  = blk & 1;                 // block-uniform
  const int pb   = (blk >> 1) * BR;         // batch-index base
  const int tid  = threadIdx.x;
  const int w    = tid >> 6;
  const int lane = tid & 63;
  const int bi   = pb + w * 64 + lane;      // this lane's batch index
  const int grow = 2 * bi + dof;            // global row

  // ---- per-lane row data -> registers (one-time) ----
  const float* __restrict__ xr = x + (size_t)grow * 27;
  const float y0s = xr[0] * scale[dof * 27];
  const float gs  = xr[1] * scale[dof * 27 + 1];
  const float dd  = gs - y0s;
  float xw[NB];
  #pragma unroll
  for (int k = 0; k < NB; ++k) xw[k] = xr[2 + k] * dd;  // fold (g-y0)

  const float* __restrict__ hb = ws2 + (size_t)dof * TS * REC;  // uniform
  float (*mt)[33] = tile[w];
  const int r2 = lane >> 5;          // flush role: which row of the pair
  const int tf = lane & 31;          // flush role: t offset

  for (int tb = 0; tb < TS; tb += 32) {
    const int tlen = (TS - tb < 32) ? (TS - tb) : 32;
    for (int toff = 0; toff < tlen; ++toff) {
      const float* __restrict__ hp = hb + (size_t)(tb + toff) * REC; // uniform
      float a0 = 0.f, a1 = 0.f;
      #pragma unroll
      for (int k = 0; k < 24; k += 2) {
        a0 = fmaf(xw[k],     hp[k],     a0);
        a1 = fmaf(xw[k + 1], hp[k + 1], a1);
      }
      a0 = fmaf(xw[24], hp[24], a0);
      mt[lane][toff] = fmaf(hp[25], y0s, fmaf(hp[26], gs, a0 + a1));
    }
    // ---- flush: 2 rows x 32 t per store instruction, coalesced 128B ----
    if (tf < tlen) {
      #pragma unroll 8
      for (int p = 0; p < 32; ++p) {
        const int r = 2 * p + r2;
        const int growr = 2 * (pb + w * 64 + r) + dof;
        out[(size_t)growr * TS + tb + tf] = mt[r][tf];
      }
    }
  }
}

extern "C" void kernel_launch(void* const* d_in, const int* in_sizes, int n_in,
                              void* d_out, int out_size, void* d_ws, size_t ws_size,
                              hipStream_t stream) {
  const float* x  = (const float*)d_in[0];
  const float* c  = (const float*)d_in[1];
  const float* s2 = (const float*)d_in[2];
  const float* sc = (const float*)d_in[3];
  float* ws2 = (float*)d_ws;   // needs 2*301*28*4 = 67,424 bytes
  float* out = (float*)d_out;

  hipLaunchKernelGGL(dmp_precompute, dim3(1), dim3(512), 0, stream,
                     c, s2, sc, ws2);
  hipLaunchKernelGGL(dmp_main, dim3((BATCH / BR) * 2), dim3(128), 0, stream,
                     x, sc, ws2, out);
}

// Round 13
// 120.180 us; speedup vs baseline: 4.5505x; 1.0269x over previous
//
#include <hip/hip_runtime.h>
#include <math.h>

namespace {
constexpr int   NB   = 25;     // basis functions
constexpr int   TS   = 301;    // time steps
constexpr int   REC  = 28;     // floats per (dof,t) record: h[25], A, B, pad
constexpr float DT   = 0.01f;
constexpr float TAU  = 3.0f;
constexpr float AX   = 2.0f;
constexpr float AZ   = 48.0f;
constexpr float BZ   = 12.0f;  // AZ/4
constexpr int   BATCH = 65536;
}

// ws2 layout: [dof][t][REC] = { H_k[t]*scale[dof*27+2+k] (k<25), A[t], B[t], 0 }
__global__ __launch_bounds__(512)
void dmp_precompute(const float* __restrict__ c, const float* __restrict__ s2,
                    const float* __restrict__ scale, float* __restrict__ ws2) {
  __shared__ float g[TS][NB];
  __shared__ float H[NB + 2][304];
  __shared__ float cS[NB], vS[NB];
  const int tid = threadIdx.x;
  if (tid < NB) { cS[tid] = c[tid]; vS[tid] = s2[tid]; }
  __syncthreads();
  const float q = 1.0f - AX / TAU * DT;   // cx multiplier per step
  for (int i = tid; i < TS; i += 512) {
    float cx = powf(q, (float)(i + 1));   // cx updated BEFORE use in ref
    float p[NB]; float sum = 0.f;
    #pragma unroll
    for (int n = 0; n < NB; ++n) {
      float d = cx - cS[n];
      p[n] = expf(-0.5f * d * d / vS[n]);
      sum += p[n];
    }
    float m = cx / sum;
    #pragma unroll
    for (int n = 0; n < NB; ++n) g[i][n] = p[n] * m;
  }
  __syncthreads();
  if (tid < NB + 2) {
    float y, gl;
    if (tid == 0)      { y = 1.f; gl = 0.f; }   // response to y0
    else if (tid == 1) { y = 0.f; gl = 1.f; }   // response to goal
    else               { y = 0.f; gl = 0.f; }   // response to unit w_n
    float z = 0.f;
    const int nn = (tid >= 2) ? (tid - 2) : 0;
    for (int t = 0; t < TS; ++t) {
      float fx = (tid >= 2) ? g[t][nn] : 0.f;
      float dy = z / TAU;
      float dz = (AZ * (BZ * (gl - y) - z) + fx) / TAU;
      y += dy * DT;
      z += dz * DT;
      H[tid][t] = y;
    }
  }
  __syncthreads();
  constexpr int TOT = 2 * TS * REC;
  for (int idx = tid; idx < TOT; idx += 512) {
    const int dof = idx / (TS * REC);
    const int rem = idx - dof * (TS * REC);
    const int t   = rem / REC;
    const int k   = rem - t * REC;
    float v;
    if (k < NB)            v = H[2 + k][t] * scale[dof * 27 + 2 + k];
    else if (k == NB)      v = H[0][t];   // A
    else if (k == NB + 1)  v = H[1][t];   // B
    else                   v = 0.f;
    ws2[idx] = v;
  }
}

// Block = 128 threads = 2 waves; lane = one row, wave covers 64 rows of
// one dof over ONE T-HALF (R12 failure: full-t mapping gives only 2048
// waves = 2 waves/SIMD -> s_load latency chain exposed; t-split doubles
// waves to 16/CU for the price of re-reading x once, ~14 MB).
// dof and t-half are blockIdx bits (provably uniform -> s_load records).
// h-records 2-deep software-pipelined: load t+1 while computing t.
// Outputs staged in per-wave [64][33] LDS tile, flushed every 32 t as
// coalesced 128 B row-chunks.
__global__ __launch_bounds__(128, 4)
void dmp_main(const float* __restrict__ x, const float* __restrict__ scale,
              const float* __restrict__ ws2, float* __restrict__ out) {
  __shared__ float tile[2][64][33];
  const int blk   = blockIdx.x;
  const int dof   = blk & 1;                // block-uniform
  const int thalf = (blk >> 1) & 1;         // block-uniform
  const int pb    = (blk >> 2) * 128;       // batch-index base
  const int tid   = threadIdx.x;
  const int w     = tid >> 6;
  const int lane  = tid & 63;
  const int bi    = pb + w * 64 + lane;     // this lane's batch index
  const int grow  = 2 * bi + dof;           // global row

  // ---- per-lane row data -> registers (one-time) ----
  const float* __restrict__ xr = x + (size_t)grow * 27;
  const float y0s = xr[0] * scale[dof * 27];
  const float gs  = xr[1] * scale[dof * 27 + 1];
  const float dd  = gs - y0s;
  float xw[NB];
  #pragma unroll
  for (int k = 0; k < NB; ++k) xw[k] = xr[2 + k] * dd;  // fold (g-y0)

  const float* __restrict__ hb = ws2 + (size_t)dof * TS * REC;  // uniform
  const int t0 = thalf ? 160 : 0;
  const int t1 = thalf ? TS : 160;
  float (*mt)[33] = tile[w];
  const int r2 = lane >> 5;          // flush role: which row of the pair
  const int tf = lane & 31;          // flush role: t offset
  float* __restrict__ outw = out + (size_t)(2 * (pb + w * 64) + dof) * TS;

  for (int tb = t0; tb < t1; tb += 32) {
    const int tlen = (t1 - tb < 32) ? (t1 - tb) : 32;
    // prime the 2-deep record pipeline
    const float4* __restrict__ cp = (const float4*)(hb + (size_t)tb * REC);
    float4 c0 = cp[0], c1 = cp[1], c2 = cp[2], c3 = cp[3],
           c4 = cp[4], c5 = cp[5], c6 = cp[6];
    for (int toff = 0; toff < tlen; ++toff) {
      const int tn = (tb + toff + 1 < TS) ? (tb + toff + 1) : (TS - 1);
      const float4* __restrict__ np = (const float4*)(hb + (size_t)tn * REC);
      const float4 n0 = np[0], n1 = np[1], n2 = np[2], n3 = np[3],
                   n4 = np[4], n5 = np[5], n6 = np[6];
      float a0, a1;
      a0 = xw[0] * c0.x;            a1 = xw[1] * c0.y;
      a0 = fmaf(xw[2],  c0.z, a0);  a1 = fmaf(xw[3],  c0.w, a1);
      a0 = fmaf(xw[4],  c1.x, a0);  a1 = fmaf(xw[5],  c1.y, a1);
      a0 = fmaf(xw[6],  c1.z, a0);  a1 = fmaf(xw[7],  c1.w, a1);
      a0 = fmaf(xw[8],  c2.x, a0);  a1 = fmaf(xw[9],  c2.y, a1);
      a0 = fmaf(xw[10], c2.z, a0);  a1 = fmaf(xw[11], c2.w, a1);
      a0 = fmaf(xw[12], c3.x, a0);  a1 = fmaf(xw[13], c3.y, a1);
      a0 = fmaf(xw[14], c3.z, a0);  a1 = fmaf(xw[15], c3.w, a1);
      a0 = fmaf(xw[16], c4.x, a0);  a1 = fmaf(xw[17], c4.y, a1);
      a0 = fmaf(xw[18], c4.z, a0);  a1 = fmaf(xw[19], c4.w, a1);
      a0 = fmaf(xw[20], c5.x, a0);  a1 = fmaf(xw[21], c5.y, a1);
      a0 = fmaf(xw[22], c5.z, a0);  a1 = fmaf(xw[23], c5.w, a1);
      a0 = fmaf(xw[24], c6.x, a0);
      mt[lane][toff] = fmaf(c6.y, y0s, fmaf(c6.z, gs, a0 + a1));
      c0 = n0; c1 = n1; c2 = n2; c3 = n3; c4 = n4; c5 = n5; c6 = n6;
    }
    // ---- flush: 2 rows x 32 t per store instruction, coalesced 128B ----
    if (tf < tlen) {
      #pragma unroll 8
      for (int p = 0; p < 32; ++p) {
        const int r = 2 * p + r2;
        outw[(size_t)(2 * r) * TS + tb + tf] = mt[r][tf];
      }
    }
  }
}

extern "C" void kernel_launch(void* const* d_in, const int* in_sizes, int n_in,
                              void* d_out, int out_size, void* d_ws, size_t ws_size,
                              hipStream_t stream) {
  const float* x  = (const float*)d_in[0];
  const float* c  = (const float*)d_in[1];
  const float* s2 = (const float*)d_in[2];
  const float* sc = (const float*)d_in[3];
  float* ws2 = (float*)d_ws;   // needs 2*301*28*4 = 67,424 bytes
  float* out = (float*)d_out;

  hipLaunchKernelGGL(dmp_precompute, dim3(1), dim3(512), 0, stream,
                     c, s2, sc, ws2);
  hipLaunchKernelGGL(dmp_main, dim3((BATCH / 128) * 4), dim3(128), 0, stream,
                     x, sc, ws2, out);
}

// Round 14
// 77.120 us; speedup vs baseline: 7.0913x; 1.5583x over previous
//
#include <hip/hip_runtime.h>
#include <math.h>

namespace {
constexpr int   NB   = 25;     // basis functions
constexpr int   TS   = 301;    // time steps
constexpr int   NTT  = 19;     // t-tiles of 16 (304)
constexpr float DT   = 0.01f;
constexpr float TAU  = 3.0f;
constexpr float AX   = 2.0f;
constexpr float AZ   = 48.0f;
constexpr float BZ   = 12.0f;  // AZ/4
constexpr int   BATCH = 65536;

typedef float  f32x4  __attribute__((ext_vector_type(4)));
typedef short  s16x8  __attribute__((ext_vector_type(8)));

__device__ inline ushort f2bf(float f) {           // RNE float->bf16
  uint u = __float_as_uint(f);
  uint r = u + 0x7fffu + ((u >> 16) & 1u);
  return (ushort)(r >> 16);
}
__device__ inline float bf2f(ushort h) {
  return __uint_as_float(((uint)h) << 16);
}
}

// ws layout (ushort8 records of 16B):
//   hi table: record[(d*NTT + tt)*64 + lane], 2432 records
//   lo table: follows at +2432 records.                 total 77,824 B
// Record (d,tt,lane): j=0..7 -> B[k = 8*(lane>>4)+j, t = tt*16 + (lane&15)]
//   B[5,t]=A_t, B[6,t]=B_t, B[7+i,t]=H_i[t]*scale[d*27+2+i], else 0.
__global__ __launch_bounds__(512)
void dmp_precompute(const float* __restrict__ c, const float* __restrict__ s2,
                    const float* __restrict__ scale, ushort* __restrict__ ws2) {
  __shared__ float g[TS][NB];
  __shared__ float H[NB + 2][304];
  __shared__ float cS[NB], vS[NB];
  const int tid = threadIdx.x;
  if (tid < NB) { cS[tid] = c[tid]; vS[tid] = s2[tid]; }
  __syncthreads();
  const float q = 1.0f - AX / TAU * DT;   // cx multiplier per step
  for (int i = tid; i < TS; i += 512) {
    float cx = powf(q, (float)(i + 1));   // cx updated BEFORE use in ref
    float p[NB]; float sum = 0.f;
    #pragma unroll
    for (int n = 0; n < NB; ++n) {
      float d = cx - cS[n];
      p[n] = expf(-0.5f * d * d / vS[n]);
      sum += p[n];
    }
    float m = cx / sum;
    #pragma unroll
    for (int n = 0; n < NB; ++n) g[i][n] = p[n] * m;
  }
  __syncthreads();
  if (tid < NB + 2) {
    float y, gl;
    if (tid == 0)      { y = 1.f; gl = 0.f; }   // response to y0
    else if (tid == 1) { y = 0.f; gl = 1.f; }   // response to goal
    else               { y = 0.f; gl = 0.f; }   // response to unit w_n
    float z = 0.f;
    const int nn = (tid >= 2) ? (tid - 2) : 0;
    for (int t = 0; t < TS; ++t) {
      float fx = (tid >= 2) ? g[t][nn] : 0.f;
      float dy = z / TAU;
      float dz = (AZ * (BZ * (gl - y) - z) + fx) / TAU;
      y += dy * DT;
      z += dz * DT;
      H[tid][t] = y;
    }
  }
  __syncthreads();
  // emit bf16 hi/lo B-fragment tables
  constexpr int NREC = 2 * NTT * 64;   // 2432
  for (int rec = tid; rec < NREC; rec += 512) {
    const int d    = rec / (NTT * 64);
    const int rem  = rec - d * (NTT * 64);
    const int tt   = rem >> 6;
    const int lane = rem & 63;
    const int kb   = (lane >> 4) * 8;
    const int t    = tt * 16 + (lane & 15);
    ushort hi8[8], lo8[8];
    #pragma unroll
    for (int j = 0; j < 8; ++j) {
      const int k = kb + j;
      float v = 0.f;
      if (t < TS) {
        if (k == 5)                 v = H[0][t];
        else if (k == 6)            v = H[1][t];
        else if (k >= 7 && k <= 31) v = H[2 + (k - 7)][t] * scale[d * 27 + 2 + (k - 7)];
      }
      const ushort h = f2bf(v);
      hi8[j] = h;
      lo8[j] = f2bf(v - bf2f(h));
    }
    ushort* dst_h = ws2 + (size_t)rec * 8;
    ushort* dst_l = ws2 + (size_t)(NREC + rec) * 8;
    #pragma unroll
    for (int j = 0; j < 8; ++j) { dst_h[j] = hi8[j]; dst_l[j] = lo8[j]; }
  }
}

// GEMM via MFMA: OUT[row,t] = sum_k A[row,k] * B_dof[k,t], K=27 pad 32.
// R2-R13 failure mode eliminated: no per-wave operand broadcasts at all --
// MFMA distributes A/B through the matrix crossbar (256 outputs / ~5cyc).
// f32 accuracy via bf16 hi/lo split: a*b ~= ah*bh + ah*bl + al*bh (3 MFMAs,
// dropped al*bl <= 2^-18 rel). Wave = 16 batch rows x one dof x 304 t.
// A-frag: lane holds A[m=lane&15, k=(lane>>4)*8+j], built from x once,
// scale and (g-y0) folded. B-frags: coalesced 16B/lane loads, L1/L2-hot.
// D: col(t)=lane&15, row=(lane>>4)*4+reg [m89-verified]. Zero LDS.
__global__ __launch_bounds__(256)
void dmp_mfma(const float* __restrict__ x, const float* __restrict__ scale,
              const ushort* __restrict__ ws2, float* __restrict__ out) {
  const int tid  = threadIdx.x;
  const int w    = tid >> 6;
  const int lane = tid & 63;
  const int d    = w & 1;
  const int rowb = blockIdx.x * 32 + (w >> 1) * 16;   // 16 batch rows
  const int m    = lane & 15;
  const int g    = lane >> 4;

  // ---- build A fragment (hi/lo) for rows rowb..rowb+15 ----
  const float* __restrict__ xr = x + (size_t)(2 * (rowb + m) + d) * 27;
  const float vs0 = scale[d * 27], vs1 = scale[d * 27 + 1];
  const float y0s = xr[0] * vs0;
  const float gs  = xr[1] * vs1;
  const float dd  = gs - y0s;
  s16x8 Ah, Al;
  #pragma unroll
  for (int j = 0; j < 8; ++j) {
    const int k   = 8 * g + j;
    const int idx = (k >= 7) ? (k - 5) : 0;      // clamp: no OOB
    const float wv = xr[idx] * dd;
    const float e  = (k < 5) ? 0.f : (k == 5) ? y0s : (k == 6) ? gs : wv;
    const ushort h = f2bf(e);
    Ah[j] = (short)h;
    Al[j] = (short)f2bf(e - bf2f(h));
  }

  constexpr int NREC = 2 * NTT * 64;
  const s16x8* __restrict__ Bh =
      (const s16x8*)ws2 + (size_t)(d * NTT) * 64 + lane;
  const s16x8* __restrict__ Bl = Bh + NREC;

  // output base for this lane's D column/rows
  float* __restrict__ ob =
      out + (size_t)(2 * (rowb + 4 * g) + d) * TS + m;

  #pragma unroll 1
  for (int tt = 0; tt < NTT; ++tt) {
    const s16x8 bh = Bh[tt * 64];
    const s16x8 bl = Bl[tt * 64];
    f32x4 acc = {0.f, 0.f, 0.f, 0.f};
    acc = __builtin_amdgcn_mfma_f32_16x16x32_bf16(Ah, bh, acc, 0, 0, 0);
    acc = __builtin_amdgcn_mfma_f32_16x16x32_bf16(Ah, bl, acc, 0, 0, 0);
    acc = __builtin_amdgcn_mfma_f32_16x16x32_bf16(Al, bh, acc, 0, 0, 0);
    const int t = tt * 16 + m;
    if (t < TS) {
      float* __restrict__ o = ob + tt * 16;
      o[0]          = acc[0];   // row 4g+0 -> out-row stride 2*TS floats
      o[2 * TS]     = acc[1];
      o[4 * TS]     = acc[2];
      o[6 * TS]     = acc[3];
    }
  }
}

extern "C" void kernel_launch(void* const* d_in, const int* in_sizes, int n_in,
                              void* d_out, int out_size, void* d_ws, size_t ws_size,
                              hipStream_t stream) {
  const float* x  = (const float*)d_in[0];
  const float* c  = (const float*)d_in[1];
  const float* s2 = (const float*)d_in[2];
  const float* sc = (const float*)d_in[3];
  ushort* ws2 = (ushort*)d_ws;   // needs 77,824 bytes
  float* out = (float*)d_out;

  hipLaunchKernelGGL(dmp_precompute, dim3(1), dim3(512), 0, stream,
                     c, s2, sc, ws2);
  hipLaunchKernelGGL(dmp_mfma, dim3(BATCH / 32), dim3(256), 0, stream,
                     x, sc, ws2, out);
}